// Round 16
// baseline (236.809 us; speedup 1.0000x reference)
//
#include <hip/hip_runtime.h>
#include <hip/hip_bf16.h>

// ---------------------------------------------------------------------------
// GCN (3x GCNConv) + dense head, bf16 MFMA.
// Round 16: revert GEMM2 to BK=64 (R15 A/B: BK=32 -> inherent 4-way LDS
// bank conflict, 51 vs 39.6 us). New: layer-1 spmm gathers fp32 x DIRECTLY
// (CHUNKS=16 keeps 2.56 MB/XCD L2 slices) -> cvt_x pass deleted from
// prep_all (12483 -> 2483 blocks, ~61 MB traffic saved). Rest = R13.
// ---------------------------------------------------------------------------

typedef __attribute__((ext_vector_type(8))) short bf16x8;
typedef __attribute__((ext_vector_type(4))) float f32x4;
typedef unsigned short u16;
typedef unsigned int u32;

#define MPAD 20096   // 157 * 128
#define AS1 __attribute__((address_space(1)))
#define AS3 __attribute__((address_space(3)))

__device__ inline u16 f2b(float f) {
  union { float f; u32 u; } x; x.f = f;
  u32 r = x.u + 0x7FFFu + ((x.u >> 16) & 1u);   // RNE
  return (u16)(r >> 16);
}
__device__ inline float b2f(u16 u) {
  union { u32 u; float f; } x; x.u = ((u32)u) << 16; return x.f;
}
__device__ inline float lo_f(u32 u) {
  union { u32 u; float f; } x; x.u = u << 16; return x.f;
}
__device__ inline float hi_f(u32 u) {
  union { u32 u; float f; } x; x.u = u & 0xFFFF0000u; return x.f;
}
__device__ inline unsigned int cvt_pk_bf16(float lo, float hi) {
  unsigned int r;
  asm("v_cvt_pk_bf16_f32 %0, %1, %2" : "=v"(r) : "v"(lo), "v"(hi));
  return r;
}
template <int N> __device__ __forceinline__ void vmw() {
  asm volatile("s_waitcnt vmcnt(%0)" :: "i"(N) : "memory");
}
// tanh(x) = (e^2x - 1)/(e^2x + 1); clamped. ~1e-7 rel err.
__device__ inline float fast_tanh(float x) {
  float cx = fminf(fmaxf(x, -9.f), 9.f);
  float e = __expf(2.f * cx);
  float d = e + 1.f, r;
  asm("v_rcp_f32 %0, %1" : "=v"(r) : "v"(d));
  return (e - 1.f) * r;
}

// ----------------------- fused prep kernel ---------------------------------

__device__ inline void wT_tile(const float* __restrict__ W, u16* __restrict__ WT,
                               int K, int N, int KPAD, int NPAD,
                               int bx, int by, float (*tile)[33]) {
  const int kb = by * 32, nb = bx * 32;
  const int tx = threadIdx.x & 31, ty = threadIdx.x >> 5;
  #pragma unroll
  for (int i = 0; i < 4; ++i) {
    int k = kb + ty + i * 8, n = nb + tx;
    tile[ty + i * 8][tx] = (k < K && n < N) ? W[(size_t)k * N + n] : 0.f;
  }
  __syncthreads();
  #pragma unroll
  for (int i = 0; i < 4; ++i) {
    int n = nb + ty + i * 8, k = kb + tx;
    WT[(size_t)n * KPAD + k] = f2b(tile[tx][ty + i * 8]);
  }
}

// segments: [0,512) W1T | [512,1024) W2T | [1024,1088) W3T | [1088,1120) Wd1T
// [1120,1152) Wd2T | 1152 bd1p | 1153 bd2p | [1154,2404) count_deg |
// [2404,2483) zero cnt2.   (cvt_x removed: spmm1 reads fp32 x directly)
__global__ __launch_bounds__(256) void prep_all(
    const float* __restrict__ W1, u16* __restrict__ w1t,
    const float* __restrict__ W2, u16* __restrict__ w2t,
    const float* __restrict__ W3, u16* __restrict__ w3t,
    const float* __restrict__ Wd1, u16* __restrict__ wd1t,
    const float* __restrict__ Wd2, u16* __restrict__ wd2t,
    const float* __restrict__ bd1, float* __restrict__ bd1p,
    const float* __restrict__ bd2, float* __restrict__ bd2p,
    const int* __restrict__ dst, int* __restrict__ cnt1,
    int* __restrict__ cnt2) {
  __shared__ float tile[32][33];
  const int b = blockIdx.x;
  const int tid = threadIdx.x;
  if (b < 512) {
    wT_tile(W1, w1t, 512, 1024, 512, 1024, b % 32, b / 32, tile);
  } else if (b < 1024) {
    int t = b - 512;  wT_tile(W2, w2t, 1024, 512, 1024, 512, t % 16, t / 16, tile);
  } else if (b < 1088) {
    int t = b - 1024; wT_tile(W3, w3t, 512, 128, 512, 128, t % 4, t / 4, tile);
  } else if (b < 1120) {
    int t = b - 1088; wT_tile(Wd1, wd1t, 128, 152, 128, 256, t % 8, t / 8, tile);
  } else if (b < 1152) {
    int t = b - 1120; wT_tile(Wd2, wd2t, 152, 48, 256, 128, t % 4, t / 4, tile);
  } else if (b == 1152) {
    bd1p[tid] = (tid < 152) ? bd1[tid] : 0.f;
  } else if (b == 1153) {
    if (tid < 128) bd2p[tid] = (tid < 48) ? bd2[tid] : 0.f;
  } else if (b < 2404) {
    int e = (b - 1154) * 256 + tid;
    if (e < 320000) atomicAdd(&cnt1[dst[e]], 1);
  } else {
    int i = (b - 2404) * 256 + tid;
    if (i < 20000) cnt2[i] = 0;
  }
}

__global__ __launch_bounds__(256) void zero_cnt(int* __restrict__ c, int n) {
  int i = blockIdx.x * 256 + threadIdx.x;
  if (i < n) c[i] = 0;
}

// ----------------------- two-level exclusive scan --------------------------
__global__ __launch_bounds__(1024) void scan_part(
    const int* __restrict__ in, int* __restrict__ out,
    int* __restrict__ bsum, int n) {
  __shared__ int wsum[16];
  const int lane = threadIdx.x & 63, wv = threadIdx.x >> 6;
  int i = blockIdx.x * 1024 + threadIdx.x;
  int v = (i < n) ? in[i] : 0;
  int s = v;
  #pragma unroll
  for (int off = 1; off < 64; off <<= 1) {
    int t = __shfl_up(s, off, 64);
    if (lane >= off) s += t;
  }
  if (lane == 63) wsum[wv] = s;
  __syncthreads();
  if (wv == 0 && lane < 16) {
    int t = wsum[lane];
    #pragma unroll
    for (int off = 1; off < 16; off <<= 1) {
      int u = __shfl_up(t, off, 64);
      if (lane >= off) t += u;
    }
    wsum[lane] = t;
  }
  __syncthreads();
  int waveoff = (wv == 0) ? 0 : wsum[wv - 1];
  if (i < n) out[i] = waveoff + s - v;
  if (threadIdx.x == 0) bsum[blockIdx.x] = wsum[15];
}
__global__ __launch_bounds__(1024) void scan_fix(
    int* __restrict__ out, const int* __restrict__ bsum, int n, int nb) {
  int b = blockIdx.x;
  int pre = 0, tot = 0;
  for (int j = 0; j < nb; ++j) {
    int v = bsum[j];
    if (j < b) pre += v;
    tot += v;
  }
  int i = b * 1024 + threadIdx.x;
  if (i < n && b > 0) out[i] += pre;
  if (b == 0 && threadIdx.x == 0) out[n] = tot;
}

// scatter edges to CSR order, packed as (bf16(w) << 16) | u16(src)
__global__ __launch_bounds__(256) void scatter_csr(
    const int* __restrict__ dst, const int* __restrict__ src,
    const float* __restrict__ ew, const int* __restrict__ row_ptr,
    int* __restrict__ cnt, u32* __restrict__ csr_pack, int E) {
  int e = blockIdx.x * 256 + threadIdx.x;
  if (e >= E) return;
  int d = dst[e];
  int pos = row_ptr[d] + atomicAdd(&cnt[d], 1);
  csr_pack[pos] = ((u32)f2b(ew[e]) << 16) | (u32)src[e];
}

// ----------------------- 128x128 2-phase MFMA GEMM --------------------------
// OMODE: 0 = f32 C, 1 = bf16 C, 2 = fused d_out = relu(C)@wd3 + bd3
template <int ACT, bool BIAS, int OMODE, int BK>
__global__ __launch_bounds__(256) void gemm_mfma_db(
    const u16* __restrict__ A, const u16* __restrict__ BT,
    const float* __restrict__ bias, void* __restrict__ C,
    int M, int K, int Nn,
    const float* __restrict__ wd3, const float* __restrict__ bd3,
    float* __restrict__ fout, int NR) {
  constexpr int NCH = BK / 16;
  constexpr int NL = 2 * NCH;
  constexpr int SWZ = BK / 8 - 1;
  constexpr int KS = BK / 32;
  __shared__ __align__(16) u16 As[2][128 * BK];
  __shared__ __align__(16) u16 Bs[2][128 * BK];
  __shared__ float rs[2][128];
  const int tid = threadIdx.x;
  const int lane = tid & 63;
  const int wave = tid >> 6;
  const int lo = lane & 15, hi = lane >> 4;
  const int wr = wave >> 1, wc = wave & 1;

  const int gx = gridDim.x;
  const int nwg = gx * gridDim.y;
  const int wg = blockIdx.y * gx + blockIdx.x;
  const int q = nwg >> 3, r = nwg & 7;
  const int xcd = wg & 7, sidx = wg >> 3;
  const int swz = (xcd < r ? xcd * (q + 1) : r * (q + 1) + (xcd - r) * q) + sidx;
  const int row0 = (swz / gx) * 128;
  const int col0 = (swz % gx) * 128;

  const u16* pa[NCH];
  const u16* pb[NCH];
  int so[NCH];
  #pragma unroll
  for (int i = 0; i < NCH; ++i) {
    int o = i * 4096 + tid * 16;
    int rr = o / (BK * 2);
    int kb = o % (BK * 2);
    int ke = (kb >> 1) ^ ((rr & SWZ) << 3);
    pa[i] = &A[(size_t)(row0 + rr) * K + ke];
    pb[i] = &BT[(size_t)(col0 + rr) * K + ke];
    so[i] = o >> 1;
  }

  const int nk = K / BK;
  f32x4 acc[4][4] = {};

  auto STAGE = [&](int buf, int kt) {
    const int ko = kt * BK;
    #pragma unroll
    for (int i = 0; i < NCH; ++i) {
      __builtin_amdgcn_global_load_lds(
          (const AS1 void*)(pa[i] + ko),
          (AS3 void*)&As[buf][so[i]], 16, 0, 0);
      __builtin_amdgcn_global_load_lds(
          (const AS1 void*)(pb[i] + ko),
          (AS3 void*)&Bs[buf][so[i]], 16, 0, 0);
    }
  };

  STAGE(0, 0);
  STAGE(1, 1);
  vmw<NL>();
  __builtin_amdgcn_s_barrier();

  auto body = [&](int cur, int kt) {
    bf16x8 af[KS][4], bfr[KS][4];
    #pragma unroll
    for (int ks = 0; ks < KS; ++ks) {
      #pragma unroll
      for (int m = 0; m < 4; ++m) {
        int row = wr * 64 + m * 16 + lo;
        int idx = (row * BK + ks * 32 + hi * 8) ^ ((row & SWZ) << 3);
        af[ks][m] = *reinterpret_cast<const bf16x8*>(&As[cur][idx]);
      }
      #pragma unroll
      for (int n = 0; n < 4; ++n) {
        int col = wc * 64 + n * 16 + lo;
        int idx = (col * BK + ks * 32 + hi * 8) ^ ((col & SWZ) << 3);
        bfr[ks][n] = *reinterpret_cast<const bf16x8*>(&Bs[cur][idx]);
      }
    }
    __builtin_amdgcn_s_setprio(1);
    #pragma unroll
    for (int ks = 0; ks < KS; ++ks)
      #pragma unroll
      for (int m = 0; m < 4; ++m)
        #pragma unroll
        for (int n = 0; n < 4; ++n)
          acc[m][n] = __builtin_amdgcn_mfma_f32_16x16x32_bf16(
              af[ks][m], bfr[ks][n], acc[m][n], 0, 0, 0);
    __builtin_amdgcn_s_setprio(0);
    asm volatile("s_waitcnt lgkmcnt(0)" ::: "memory");
    __builtin_amdgcn_s_barrier();
    if (kt + 2 < nk) {
      STAGE(cur, kt + 2);
      vmw<NL>();
    } else if (kt + 1 < nk) {
      vmw<0>();
    }
    __builtin_amdgcn_s_barrier();
  };

  for (int kt = 0; kt < nk; kt += 2) {   // all nk are even
    body(0, kt);
    body(1, kt + 1);
  }

  float bv[4];
  if (BIAS) {
    #pragma unroll
    for (int n = 0; n < 4; ++n) bv[n] = bias[col0 + wc * 64 + n * 16 + lo];
  }
  float w3v[4];
  if (OMODE == 2) {
    #pragma unroll
    for (int n = 0; n < 4; ++n) {
      int c = wc * 64 + n * 16 + lo;
      w3v[n] = (c < 48) ? wd3[c] : 0.f;
    }
  }

  u16* Cb = (u16*)C;
  float* Cf = (float*)C;
  float pp[4][4] = {};
  #pragma unroll
  for (int m = 0; m < 4; ++m) {
    int rbase = row0 + wr * 64 + m * 16 + hi * 4;
    #pragma unroll
    for (int n = 0; n < 4; ++n) {
      int c = col0 + wc * 64 + n * 16 + lo;
      float vv[4];
      #pragma unroll
      for (int i = 0; i < 4; ++i) {
        float v = acc[m][n][i];
        if (BIAS) v += bv[n];
        if (ACT == 1) v = fast_tanh(v);
        else if (ACT == 2) v = fmaxf(v, 0.f);
        vv[i] = v;
        if (OMODE == 2) pp[m][i] += v * w3v[n];
      }
      if (OMODE == 1) {
        unsigned int r01 = cvt_pk_bf16(vv[0], vv[1]);
        unsigned int r23 = cvt_pk_bf16(vv[2], vv[3]);
        u16* p = Cb + (size_t)rbase * Nn + c;
        p[0]              = (u16)r01;
        p[Nn]             = (u16)(r01 >> 16);
        p[2 * (size_t)Nn] = (u16)r23;
        p[3 * (size_t)Nn] = (u16)(r23 >> 16);
      } else if (OMODE == 0) {
        float* p = Cf + (size_t)rbase * Nn + c;
        p[0] = vv[0]; p[Nn] = vv[1];
        p[2 * (size_t)Nn] = vv[2]; p[3 * (size_t)Nn] = vv[3];
      }
    }
  }

  if (OMODE == 2) {
    #pragma unroll
    for (int m = 0; m < 4; ++m) {
      #pragma unroll
      for (int i = 0; i < 4; ++i) {
        float p = pp[m][i];
        p += __shfl_xor(p, 1, 16);
        p += __shfl_xor(p, 2, 16);
        p += __shfl_xor(p, 4, 16);
        p += __shfl_xor(p, 8, 16);
        if (lo == 0) rs[wc][wr * 64 + m * 16 + hi * 4 + i] = p;
      }
    }
    __syncthreads();
    if (tid < 128) {
      int rr2 = row0 + tid;
      if (rr2 < NR) fout[rr2] = rs[0][tid] + rs[1][tid] + bd3[0];
    }
  }
}

// ----------------------- spmm: pipelined, XCD-sharded (bf16 H, R13) ---------
template <int F, int CHUNKS, int ACT, bool BIAS, bool OUT_BF16>
__global__ __launch_bounds__(256) void spmm_pl(
    const int* __restrict__ row_ptr, const u32* __restrict__ pack,
    const u16* __restrict__ H, const float* __restrict__ bias,
    void* __restrict__ out, int N) {
  const int ci = blockIdx.x % CHUNKS;
  const int nb = blockIdx.x / CHUNKS;
  const int g = threadIdx.x >> 3;          // 32 nodes/block
  const int gl = threadIdx.x & 7;
  const int node = nb * 32 + g;
  if (node >= N) return;
  const int c0 = ci * (F / CHUNKS) + gl * 8;
  const int beg = row_ptr[node], end = row_ptr[node + 1];

  float a[8] = {};
  int p = beg;
  u32 k0 = 0, k1 = 0, k2 = 0, k3 = 0;
  bool have = (p + 4 <= end);
  if (have) { k0 = pack[p]; k1 = pack[p + 1]; k2 = pack[p + 2]; k3 = pack[p + 3]; }
  while (have) {
    int pn = p + 4;
    bool haven = (pn + 4 <= end);
    u32 n0 = 0, n1 = 0, n2 = 0, n3 = 0;
    if (haven) { n0 = pack[pn]; n1 = pack[pn + 1]; n2 = pack[pn + 2]; n3 = pack[pn + 3]; }
    uint4 h0 = *reinterpret_cast<const uint4*>(&H[(size_t)(k0 & 0xFFFFu) * F + c0]);
    uint4 h1 = *reinterpret_cast<const uint4*>(&H[(size_t)(k1 & 0xFFFFu) * F + c0]);
    uint4 h2 = *reinterpret_cast<const uint4*>(&H[(size_t)(k2 & 0xFFFFu) * F + c0]);
    uint4 h3 = *reinterpret_cast<const uint4*>(&H[(size_t)(k3 & 0xFFFFu) * F + c0]);
    float w0 = hi_f(k0), w1 = hi_f(k1), w2 = hi_f(k2), w3 = hi_f(k3);
    a[0] += w0 * lo_f(h0.x) + w1 * lo_f(h1.x) + w2 * lo_f(h2.x) + w3 * lo_f(h3.x);
    a[1] += w0 * hi_f(h0.x) + w1 * hi_f(h1.x) + w2 * hi_f(h2.x) + w3 * hi_f(h3.x);
    a[2] += w0 * lo_f(h0.y) + w1 * lo_f(h1.y) + w2 * lo_f(h2.y) + w3 * lo_f(h3.y);
    a[3] += w0 * hi_f(h0.y) + w1 * hi_f(h1.y) + w2 * hi_f(h2.y) + w3 * hi_f(h3.y);
    a[4] += w0 * lo_f(h0.z) + w1 * lo_f(h1.z) + w2 * lo_f(h2.z) + w3 * lo_f(h3.z);
    a[5] += w0 * hi_f(h0.z) + w1 * hi_f(h1.z) + w2 * hi_f(h2.z) + w3 * hi_f(h3.z);
    a[6] += w0 * lo_f(h0.w) + w1 * lo_f(h1.w) + w2 * lo_f(h2.w) + w3 * lo_f(h3.w);
    a[7] += w0 * hi_f(h0.w) + w1 * hi_f(h1.w) + w2 * hi_f(h2.w) + w3 * hi_f(h3.w);
    p = pn; k0 = n0; k1 = n1; k2 = n2; k3 = n3; have = haven;
  }
  for (; p < end; ++p) {
    u32 k = pack[p];
    uint4 hv = *reinterpret_cast<const uint4*>(&H[(size_t)(k & 0xFFFFu) * F + c0]);
    float wt = hi_f(k);
    a[0] += wt * lo_f(hv.x); a[1] += wt * hi_f(hv.x);
    a[2] += wt * lo_f(hv.y); a[3] += wt * hi_f(hv.y);
    a[4] += wt * lo_f(hv.z); a[5] += wt * hi_f(hv.z);
    a[6] += wt * lo_f(hv.w); a[7] += wt * hi_f(hv.w);
  }
  if (BIAS) {
    #pragma unroll
    for (int k = 0; k < 8; ++k) a[k] += bias[c0 + k];
  }
  if (ACT == 1) {
    #pragma unroll
    for (int k = 0; k < 8; ++k) a[k] = fast_tanh(a[k]);
  }
  if (OUT_BF16) {
    uint4 o;
    o.x = cvt_pk_bf16(a[0], a[1]);
    o.y = cvt_pk_bf16(a[2], a[3]);
    o.z = cvt_pk_bf16(a[4], a[5]);
    o.w = cvt_pk_bf16(a[6], a[7]);
    *reinterpret_cast<uint4*>(&((u16*)out)[(size_t)node * F + c0]) = o;
  } else {
    float* op = &((float*)out)[(size_t)node * F + c0];
    #pragma unroll
    for (int k = 0; k < 8; ++k) op[k] = a[k];
  }
}

// ----------------------- spmm: fp32 input (layer 1, reads x directly) -------
// CHUNKS=16 -> 32-col fp32 slices = 2.56 MB/XCD (fits 4 MB L2).
// 8 lanes/node x 4 cols (float4 16B gathers), 32 nodes/block.
__global__ __launch_bounds__(256) void spmm_f32in(
    const int* __restrict__ row_ptr, const u32* __restrict__ pack,
    const float* __restrict__ X, u16* __restrict__ out, int N) {
  const int ci = blockIdx.x & 15;
  const int nb = blockIdx.x >> 4;
  const int g = threadIdx.x >> 3;          // 32 nodes/block
  const int gl = threadIdx.x & 7;
  const int node = nb * 32 + g;
  if (node >= N) return;
  const int c0 = ci * 32 + gl * 4;
  const float* Xc = X + c0;
  const int beg = row_ptr[node], end = row_ptr[node + 1];

  float a0 = 0.f, a1 = 0.f, a2 = 0.f, a3 = 0.f;
  int p = beg;
  u32 k0 = 0, k1 = 0, k2 = 0, k3 = 0;
  bool have = (p + 4 <= end);
  if (have) { k0 = pack[p]; k1 = pack[p + 1]; k2 = pack[p + 2]; k3 = pack[p + 3]; }
  while (have) {
    int pn = p + 4;
    bool haven = (pn + 4 <= end);
    u32 n0 = 0, n1 = 0, n2 = 0, n3 = 0;
    if (haven) { n0 = pack[pn]; n1 = pack[pn + 1]; n2 = pack[pn + 2]; n3 = pack[pn + 3]; }
    float4 h0 = *reinterpret_cast<const float4*>(&Xc[(size_t)(k0 & 0xFFFFu) * 512]);
    float4 h1 = *reinterpret_cast<const float4*>(&Xc[(size_t)(k1 & 0xFFFFu) * 512]);
    float4 h2 = *reinterpret_cast<const float4*>(&Xc[(size_t)(k2 & 0xFFFFu) * 512]);
    float4 h3 = *reinterpret_cast<const float4*>(&Xc[(size_t)(k3 & 0xFFFFu) * 512]);
    float w0 = hi_f(k0), w1 = hi_f(k1), w2 = hi_f(k2), w3 = hi_f(k3);
    a0 += w0 * h0.x + w1 * h1.x + w2 * h2.x + w3 * h3.x;
    a1 += w0 * h0.y + w1 * h1.y + w2 * h2.y + w3 * h3.y;
    a2 += w0 * h0.z + w1 * h1.z + w2 * h2.z + w3 * h3.z;
    a3 += w0 * h0.w + w1 * h1.w + w2 * h2.w + w3 * h3.w;
    p = pn; k0 = n0; k1 = n1; k2 = n2; k3 = n3; have = haven;
  }
  for (; p < end; ++p) {
    u32 k = pack[p];
    float4 hv = *reinterpret_cast<const float4*>(&Xc[(size_t)(k & 0xFFFFu) * 512]);
    float wt = hi_f(k);
    a0 += wt * hv.x; a1 += wt * hv.y; a2 += wt * hv.z; a3 += wt * hv.w;
  }
  uint2 o;
  o.x = cvt_pk_bf16(a0, a1);
  o.y = cvt_pk_bf16(a2, a3);
  *reinterpret_cast<uint2*>(&out[(size_t)node * 512 + c0]) = o;
}

// ---------------------------------------------------------------------------

extern "C" void kernel_launch(void* const* d_in, const int* in_sizes, int n_in,
                              void* d_out, int out_size, void* d_ws, size_t ws_size,
                              hipStream_t stream) {
  const int N = 20000, E = 320000;
  const int F_IN = 512, H1 = 1024, H2 = 512, F_OUT = 128;
  const int D1P = 256, D2P = 128;

  const float* x    = (const float*)d_in[0];
  const int*   src  = (const int*)d_in[1];
  const int*   dst  = (const int*)d_in[2];
  const float* ew   = (const float*)d_in[3];
  const float* W1   = (const float*)d_in[4];
  const float* b1   = (const float*)d_in[5];
  const float* W2   = (const float*)d_in[6];
  const float* b2   = (const float*)d_in[7];
  const float* W3   = (const float*)d_in[8];
  const float* b3   = (const float*)d_in[9];
  const float* Wd1  = (const float*)d_in[10];
  const float* bd1  = (const float*)d_in[11];
  const float* Wd2  = (const float*)d_in[12];
  const float* bd2  = (const float*)d_in[13];
  const float* Wd3  = (const float*)d_in[14];
  const float* bd3  = (const float*)d_in[15];
  float* out = (float*)d_out;

  size_t off = 0;
  auto alloc = [&](size_t bytes) {
    void* p = (char*)d_ws + off;
    off += (bytes + 255) & ~(size_t)255;
    return p;
  };
  u16* t2   = (u16*)alloc((size_t)MPAD * F_IN * 2);    // GEMM2 out (bf16)
  u16* ax   = (u16*)alloc((size_t)MPAD * F_IN * 2);    // A@x;   later h2
  u16* h1   = (u16*)alloc((size_t)MPAD * H1 * 2);      // h1 (also t3,gb,d1 region)
  u16* w1t  = (u16*)alloc((size_t)H1 * F_IN * 2);
  u16* w2t  = (u16*)alloc((size_t)H2 * H1 * 2);
  u16* w3t  = (u16*)alloc((size_t)F_OUT * H2 * 2);
  u16* wd1t = (u16*)alloc((size_t)D1P * F_OUT * 2);
  u16* wd2t = (u16*)alloc((size_t)D2P * D1P * 2);
  float* bd1p = (float*)alloc((size_t)D1P * 4);
  float* bd2p = (float*)alloc((size_t)D2P * 4);
  int* row_ptr = (int*)alloc((size_t)(N + 1) * 4);
  int* cnt1    = (int*)alloc((size_t)N * 4);
  int* cnt2    = (int*)alloc((size_t)N * 4);
  int* bsum    = (int*)alloc((size_t)32 * 4);
  u32* csr_pack = (u32*)alloc((size_t)E * 4);

  u16* h2 = ax;
  u16* t3 = h1;
  u16* gb = t3 + (size_t)MPAD * F_OUT;
  u16* d1 = gb + (size_t)MPAD * F_OUT;

  auto cdiv = [](int a, int b) { return (a + b - 1) / b; };
  const int NB32 = cdiv(N, 32);   // 625

  // ---- prep ----
  zero_cnt<<<cdiv(N, 256), 256, 0, stream>>>(cnt1, N);
  prep_all<<<2483, 256, 0, stream>>>(W1, w1t, W2, w2t, W3, w3t,
                                     Wd1, wd1t, Wd2, wd2t, bd1, bd1p,
                                     bd2, bd2p, dst, cnt1, cnt2);
  scan_part<<<20, 1024, 0, stream>>>(cnt1, row_ptr, bsum, N);
  scan_fix<<<20, 1024, 0, stream>>>(row_ptr, bsum, N, 20);
  scatter_csr<<<cdiv(E, 256), 256, 0, stream>>>(dst, src, ew, row_ptr, cnt2,
                                                csr_pack, E);

  // ---- layer 1 (reordered): ax = A@x (fp32 gather) ; h1 = tanh(ax@W1+b1) ----
  spmm_f32in<<<NB32 * 16, 256, 0, stream>>>(row_ptr, csr_pack, x, ax, N);
  gemm_mfma_db<1, true, 1, 64><<<dim3(H1 / 128, MPAD / 128), 256, 0, stream>>>(
      ax, w1t, b1, h1, MPAD, F_IN, H1, nullptr, nullptr, nullptr, 0);

  // ---- layer 2: t2 = h1@W2 ; h2 = tanh(A@t2 + b2) ----
  gemm_mfma_db<0, false, 1, 64><<<dim3(H2 / 128, MPAD / 128), 256, 0, stream>>>(
      h1, w2t, nullptr, t2, MPAD, H1, H2, nullptr, nullptr, nullptr, 0);
  spmm_pl<512, 8, 1, true, true><<<NB32 * 8, 256, 0, stream>>>(
      row_ptr, csr_pack, t2, b2, h2, N);

  // ---- layer 3: t3 = h2@W3 ; gb = A@t3 + b3 (bf16) ----
  gemm_mfma_db<0, false, 1, 64><<<dim3(F_OUT / 128, MPAD / 128), 256, 0, stream>>>(
      h2, w3t, nullptr, t3, MPAD, H2, F_OUT, nullptr, nullptr, nullptr, 0);
  spmm_pl<128, 2, 0, true, true><<<NB32 * 2, 256, 0, stream>>>(
      row_ptr, csr_pack, t3, b3, gb, N);

  // ---- dense head: d1 = relu(gb@Wd1+bd1); out = relu(d1@Wd2+bd2)@Wd3+bd3 ----
  gemm_mfma_db<2, true, 1, 64><<<dim3(D1P / 128, MPAD / 128), 256, 0, stream>>>(
      gb, wd1t, bd1p, d1, MPAD, F_OUT, D1P, nullptr, nullptr, nullptr, 0);
  gemm_mfma_db<2, true, 2, 64><<<dim3(D2P / 128, MPAD / 128), 256, 0, stream>>>(
      d1, wd2t, bd2p, nullptr, MPAD, D1P, D2P, Wd3, bd3, out, N);
}

// Round 17
// 215.997 us; speedup vs baseline: 1.0964x; 1.0964x over previous
//
#include <hip/hip_runtime.h>
#include <hip/hip_bf16.h>

// ---------------------------------------------------------------------------
// GCN (3x GCNConv) + dense head, bf16 MFMA.
// Round 17: REVERT to the proven R13 configuration (215.8 us). R14/R15/R16
// levers all falsified with mechanisms: gather-rotation (+VALU > latency),
// BK=32 (4-way LDS bank conflict), fp32-direct spmm (2x2.56MB/XCD > 4MB L2).
// R13 = zero_cnt compute kernel, fused prep (incl. cvt_x), two-level scan,
// packed CSR, XCD-sharded pack-prefetch spmm, 128^2 2-phase BK=64 MFMA GEMM,
// head fused (last layer in GEMM epilogue).
// ---------------------------------------------------------------------------

typedef __attribute__((ext_vector_type(8))) short bf16x8;
typedef __attribute__((ext_vector_type(4))) float f32x4;
typedef unsigned short u16;
typedef unsigned int u32;

#define MPAD 20096   // 157 * 128
#define AS1 __attribute__((address_space(1)))
#define AS3 __attribute__((address_space(3)))

__device__ inline u16 f2b(float f) {
  union { float f; u32 u; } x; x.f = f;
  u32 r = x.u + 0x7FFFu + ((x.u >> 16) & 1u);   // RNE
  return (u16)(r >> 16);
}
__device__ inline float b2f(u16 u) {
  union { u32 u; float f; } x; x.u = ((u32)u) << 16; return x.f;
}
__device__ inline float lo_f(u32 u) {
  union { u32 u; float f; } x; x.u = u << 16; return x.f;
}
__device__ inline float hi_f(u32 u) {
  union { u32 u; float f; } x; x.u = u & 0xFFFF0000u; return x.f;
}
__device__ inline unsigned int cvt_pk_bf16(float lo, float hi) {
  unsigned int r;
  asm("v_cvt_pk_bf16_f32 %0, %1, %2" : "=v"(r) : "v"(lo), "v"(hi));
  return r;
}
// tanh(x) = (e^2x - 1)/(e^2x + 1); clamped. ~1e-7 rel err.
__device__ inline float fast_tanh(float x) {
  float cx = fminf(fmaxf(x, -9.f), 9.f);
  float e = __expf(2.f * cx);
  float d = e + 1.f, r;
  asm("v_rcp_f32 %0, %1" : "=v"(r) : "v"(d));
  return (e - 1.f) * r;
}

// ----------------------- fused prep kernel ---------------------------------

__device__ inline void wT_tile(const float* __restrict__ W, u16* __restrict__ WT,
                               int K, int N, int KPAD, int NPAD,
                               int bx, int by, float (*tile)[33]) {
  const int kb = by * 32, nb = bx * 32;
  const int tx = threadIdx.x & 31, ty = threadIdx.x >> 5;
  #pragma unroll
  for (int i = 0; i < 4; ++i) {
    int k = kb + ty + i * 8, n = nb + tx;
    tile[ty + i * 8][tx] = (k < K && n < N) ? W[(size_t)k * N + n] : 0.f;
  }
  __syncthreads();
  #pragma unroll
  for (int i = 0; i < 4; ++i) {
    int n = nb + ty + i * 8, k = kb + tx;
    WT[(size_t)n * KPAD + k] = f2b(tile[tx][ty + i * 8]);
  }
}

__global__ __launch_bounds__(256) void prep_all(
    const float* __restrict__ x, u16* __restrict__ xb,
    const float* __restrict__ W1, u16* __restrict__ w1t,
    const float* __restrict__ W2, u16* __restrict__ w2t,
    const float* __restrict__ W3, u16* __restrict__ w3t,
    const float* __restrict__ Wd1, u16* __restrict__ wd1t,
    const float* __restrict__ Wd2, u16* __restrict__ wd2t,
    const float* __restrict__ bd1, float* __restrict__ bd1p,
    const float* __restrict__ bd2, float* __restrict__ bd2p,
    const int* __restrict__ dst, int* __restrict__ cnt1,
    int* __restrict__ cnt2) {
  __shared__ float tile[32][33];
  const int b = blockIdx.x;
  const int tid = threadIdx.x;
  if (b < 512) {
    wT_tile(W1, w1t, 512, 1024, 512, 1024, b % 32, b / 32, tile);
  } else if (b < 1024) {
    int t = b - 512;  wT_tile(W2, w2t, 1024, 512, 1024, 512, t % 16, t / 16, tile);
  } else if (b < 1088) {
    int t = b - 1024; wT_tile(W3, w3t, 512, 128, 512, 128, t % 4, t / 4, tile);
  } else if (b < 1120) {
    int t = b - 1088; wT_tile(Wd1, wd1t, 128, 152, 128, 256, t % 8, t / 8, tile);
  } else if (b < 1152) {
    int t = b - 1120; wT_tile(Wd2, wd2t, 152, 48, 256, 128, t % 4, t / 4, tile);
  } else if (b < 11152) {
    int idx = ((b - 1152) * 256 + tid) * 4;
    if (idx < 20000 * 512) {
      float4 v = *reinterpret_cast<const float4*>(&x[idx]);
      uint2 o;
      o.x = cvt_pk_bf16(v.x, v.y);
      o.y = cvt_pk_bf16(v.z, v.w);
      *reinterpret_cast<uint2*>(&xb[idx]) = o;
    }
  } else if (b == 11152) {
    bd1p[tid] = (tid < 152) ? bd1[tid] : 0.f;
  } else if (b == 11153) {
    if (tid < 128) bd2p[tid] = (tid < 48) ? bd2[tid] : 0.f;
  } else if (b < 12404) {
    int e = (b - 11154) * 256 + tid;
    if (e < 320000) atomicAdd(&cnt1[dst[e]], 1);
  } else {
    int i = (b - 12404) * 256 + tid;
    if (i < 20000) cnt2[i] = 0;
  }
}

// zero cnt1 as a COMPUTE kernel (avoids a graph memset node)
__global__ __launch_bounds__(256) void zero_cnt(int* __restrict__ c, int n) {
  int i = blockIdx.x * 256 + threadIdx.x;
  if (i < n) c[i] = 0;
}

// ----------------------- two-level exclusive scan --------------------------
__global__ __launch_bounds__(1024) void scan_part(
    const int* __restrict__ in, int* __restrict__ out,
    int* __restrict__ bsum, int n) {
  __shared__ int wsum[16];
  const int lane = threadIdx.x & 63, wv = threadIdx.x >> 6;
  int i = blockIdx.x * 1024 + threadIdx.x;
  int v = (i < n) ? in[i] : 0;
  int s = v;
  #pragma unroll
  for (int off = 1; off < 64; off <<= 1) {
    int t = __shfl_up(s, off, 64);
    if (lane >= off) s += t;
  }
  if (lane == 63) wsum[wv] = s;
  __syncthreads();
  if (wv == 0 && lane < 16) {
    int t = wsum[lane];
    #pragma unroll
    for (int off = 1; off < 16; off <<= 1) {
      int u = __shfl_up(t, off, 64);
      if (lane >= off) t += u;
    }
    wsum[lane] = t;
  }
  __syncthreads();
  int waveoff = (wv == 0) ? 0 : wsum[wv - 1];
  if (i < n) out[i] = waveoff + s - v;
  if (threadIdx.x == 0) bsum[blockIdx.x] = wsum[15];
}
__global__ __launch_bounds__(1024) void scan_fix(
    int* __restrict__ out, const int* __restrict__ bsum, int n, int nb) {
  int b = blockIdx.x;
  int pre = 0, tot = 0;
  for (int j = 0; j < nb; ++j) {
    int v = bsum[j];
    if (j < b) pre += v;
    tot += v;
  }
  int i = b * 1024 + threadIdx.x;
  if (i < n && b > 0) out[i] += pre;
  if (b == 0 && threadIdx.x == 0) out[n] = tot;
}

// scatter edges to CSR order, packed as (bf16(w) << 16) | u16(src)
__global__ __launch_bounds__(256) void scatter_csr(
    const int* __restrict__ dst, const int* __restrict__ src,
    const float* __restrict__ ew, const int* __restrict__ row_ptr,
    int* __restrict__ cnt, u32* __restrict__ csr_pack, int E) {
  int e = blockIdx.x * 256 + threadIdx.x;
  if (e >= E) return;
  int d = dst[e];
  int pos = row_ptr[d] + atomicAdd(&cnt[d], 1);
  csr_pack[pos] = ((u32)f2b(ew[e]) << 16) | (u32)src[e];
}

// ----------------------- 128x128 2-phase MFMA GEMM --------------------------
// OMODE: 0 = f32 C, 1 = bf16 C, 2 = fused d_out = relu(C)@wd3 + bd3
template <int ACT, bool BIAS, int OMODE>
__global__ __launch_bounds__(256) void gemm_mfma_db(
    const u16* __restrict__ A, const u16* __restrict__ BT,
    const float* __restrict__ bias, void* __restrict__ C,
    int M, int K, int Nn,
    const float* __restrict__ wd3, const float* __restrict__ bd3,
    float* __restrict__ fout, int NR) {
  __shared__ __align__(16) u16 As[2][128 * 64];
  __shared__ __align__(16) u16 Bs[2][128 * 64];
  __shared__ float rs[2][128];
  const int tid = threadIdx.x;
  const int lane = tid & 63;
  const int wave = tid >> 6;
  const int lo = lane & 15, hi = lane >> 4;
  const int wr = wave >> 1, wc = wave & 1;

  const int gx = gridDim.x;
  const int nwg = gx * gridDim.y;
  const int wg = blockIdx.y * gx + blockIdx.x;
  const int q = nwg >> 3, r = nwg & 7;
  const int xcd = wg & 7, sidx = wg >> 3;
  const int swz = (xcd < r ? xcd * (q + 1) : r * (q + 1) + (xcd - r) * q) + sidx;
  const int row0 = (swz / gx) * 128;
  const int col0 = (swz % gx) * 128;

  const u16* pa[4];
  const u16* pb[4];
  int so[4];
  #pragma unroll
  for (int i = 0; i < 4; ++i) {
    int o = i * 4096 + tid * 16;
    int rr = o >> 7;
    int ke = ((o & 127) >> 1) ^ ((rr & 7) << 3);
    pa[i] = &A[(size_t)(row0 + rr) * K + ke];
    pb[i] = &BT[(size_t)(col0 + rr) * K + ke];
    so[i] = o >> 1;
  }

  const int nk = K >> 6;
  f32x4 acc[4][4] = {};

  auto STAGE = [&](int buf, int kt) {
    const int ko = kt << 6;
    #pragma unroll
    for (int i = 0; i < 4; ++i) {
      __builtin_amdgcn_global_load_lds(
          (const AS1 void*)(pa[i] + ko),
          (AS3 void*)&As[buf][so[i]], 16, 0, 0);
      __builtin_amdgcn_global_load_lds(
          (const AS1 void*)(pb[i] + ko),
          (AS3 void*)&Bs[buf][so[i]], 16, 0, 0);
    }
  };

  STAGE(0, 0);
  STAGE(1, 1);
  asm volatile("s_waitcnt vmcnt(8)" ::: "memory");
  __builtin_amdgcn_s_barrier();

  auto body = [&](int cur, int kt) {
    bf16x8 af[2][4], bfr[2][4];
    #pragma unroll
    for (int ks = 0; ks < 2; ++ks) {
      #pragma unroll
      for (int m = 0; m < 4; ++m) {
        int row = wr * 64 + m * 16 + lo;
        int idx = (row * 64 + ks * 32 + hi * 8) ^ ((row & 7) << 3);
        af[ks][m] = *reinterpret_cast<const bf16x8*>(&As[cur][idx]);
      }
      #pragma unroll
      for (int n = 0; n < 4; ++n) {
        int col = wc * 64 + n * 16 + lo;
        int idx = (col * 64 + ks * 32 + hi * 8) ^ ((col & 7) << 3);
        bfr[ks][n] = *reinterpret_cast<const bf16x8*>(&Bs[cur][idx]);
      }
    }
    __builtin_amdgcn_s_setprio(1);
    #pragma unroll
    for (int ks = 0; ks < 2; ++ks)
      #pragma unroll
      for (int m = 0; m < 4; ++m)
        #pragma unroll
        for (int n = 0; n < 4; ++n)
          acc[m][n] = __builtin_amdgcn_mfma_f32_16x16x32_bf16(
              af[ks][m], bfr[ks][n], acc[m][n], 0, 0, 0);
    __builtin_amdgcn_s_setprio(0);
    asm volatile("s_waitcnt lgkmcnt(0)" ::: "memory");
    __builtin_amdgcn_s_barrier();
    if (kt + 2 < nk) {
      STAGE(cur, kt + 2);
      asm volatile("s_waitcnt vmcnt(8)" ::: "memory");
    } else if (kt + 1 < nk) {
      asm volatile("s_waitcnt vmcnt(0)" ::: "memory");
    }
    __builtin_amdgcn_s_barrier();
  };

  for (int kt = 0; kt < nk; kt += 2) {   // all nk are even (2,4,8,16)
    body(0, kt);
    body(1, kt + 1);
  }

  float bv[4];
  if (BIAS) {
    #pragma unroll
    for (int n = 0; n < 4; ++n) bv[n] = bias[col0 + wc * 64 + n * 16 + lo];
  }
  float w3v[4];
  if (OMODE == 2) {
    #pragma unroll
    for (int n = 0; n < 4; ++n) {
      int c = wc * 64 + n * 16 + lo;
      w3v[n] = (c < 48) ? wd3[c] : 0.f;
    }
  }

  u16* Cb = (u16*)C;
  float* Cf = (float*)C;
  float pp[4][4] = {};
  #pragma unroll
  for (int m = 0; m < 4; ++m) {
    int rbase = row0 + wr * 64 + m * 16 + hi * 4;
    #pragma unroll
    for (int n = 0; n < 4; ++n) {
      int c = col0 + wc * 64 + n * 16 + lo;
      float vv[4];
      #pragma unroll
      for (int i = 0; i < 4; ++i) {
        float v = acc[m][n][i];
        if (BIAS) v += bv[n];
        if (ACT == 1) v = fast_tanh(v);
        else if (ACT == 2) v = fmaxf(v, 0.f);
        vv[i] = v;
        if (OMODE == 2) pp[m][i] += v * w3v[n];
      }
      if (OMODE == 1) {
        unsigned int r01 = cvt_pk_bf16(vv[0], vv[1]);
        unsigned int r23 = cvt_pk_bf16(vv[2], vv[3]);
        u16* p = Cb + (size_t)rbase * Nn + c;
        p[0]              = (u16)r01;
        p[Nn]             = (u16)(r01 >> 16);
        p[2 * (size_t)Nn] = (u16)r23;
        p[3 * (size_t)Nn] = (u16)(r23 >> 16);
      } else if (OMODE == 0) {
        float* p = Cf + (size_t)rbase * Nn + c;
        p[0] = vv[0]; p[Nn] = vv[1];
        p[2 * (size_t)Nn] = vv[2]; p[3 * (size_t)Nn] = vv[3];
      }
    }
  }

  if (OMODE == 2) {
    #pragma unroll
    for (int m = 0; m < 4; ++m) {
      #pragma unroll
      for (int i = 0; i < 4; ++i) {
        float p = pp[m][i];
        p += __shfl_xor(p, 1, 16);
        p += __shfl_xor(p, 2, 16);
        p += __shfl_xor(p, 4, 16);
        p += __shfl_xor(p, 8, 16);
        if (lo == 0) rs[wc][wr * 64 + m * 16 + hi * 4 + i] = p;
      }
    }
    __syncthreads();
    if (tid < 128) {
      int rr2 = row0 + tid;
      if (rr2 < NR) fout[rr2] = rs[0][tid] + rs[1][tid] + bd3[0];
    }
  }
}

// ----------------------- spmm: pipelined, XCD-sharded -----------------------
template <int F, int CHUNKS, int ACT, bool BIAS, bool OUT_BF16>
__global__ __launch_bounds__(256) void spmm_pl(
    const int* __restrict__ row_ptr, const u32* __restrict__ pack,
    const u16* __restrict__ H, const float* __restrict__ bias,
    void* __restrict__ out, int N) {
  const int ci = blockIdx.x % CHUNKS;
  const int nb = blockIdx.x / CHUNKS;
  const int g = threadIdx.x >> 3;          // 32 nodes/block
  const int gl = threadIdx.x & 7;
  const int node = nb * 32 + g;
  if (node >= N) return;
  const int c0 = ci * (F / CHUNKS) + gl * 8;
  const int beg = row_ptr[node], end = row_ptr[node + 1];

  float a[8] = {};
  int p = beg;
  u32 k0 = 0, k1 = 0, k2 = 0, k3 = 0;
  bool have = (p + 4 <= end);
  if (have) { k0 = pack[p]; k1 = pack[p + 1]; k2 = pack[p + 2]; k3 = pack[p + 3]; }
  while (have) {
    int pn = p + 4;
    bool haven = (pn + 4 <= end);
    u32 n0 = 0, n1 = 0, n2 = 0, n3 = 0;
    if (haven) { n0 = pack[pn]; n1 = pack[pn + 1]; n2 = pack[pn + 2]; n3 = pack[pn + 3]; }
    uint4 h0 = *reinterpret_cast<const uint4*>(&H[(size_t)(k0 & 0xFFFFu) * F + c0]);
    uint4 h1 = *reinterpret_cast<const uint4*>(&H[(size_t)(k1 & 0xFFFFu) * F + c0]);
    uint4 h2 = *reinterpret_cast<const uint4*>(&H[(size_t)(k2 & 0xFFFFu) * F + c0]);
    uint4 h3 = *reinterpret_cast<const uint4*>(&H[(size_t)(k3 & 0xFFFFu) * F + c0]);
    float w0 = hi_f(k0), w1 = hi_f(k1), w2 = hi_f(k2), w3 = hi_f(k3);
    a[0] += w0 * lo_f(h0.x) + w1 * lo_f(h1.x) + w2 * lo_f(h2.x) + w3 * lo_f(h3.x);
    a[1] += w0 * hi_f(h0.x) + w1 * hi_f(h1.x) + w2 * hi_f(h2.x) + w3 * hi_f(h3.x);
    a[2] += w0 * lo_f(h0.y) + w1 * lo_f(h1.y) + w2 * lo_f(h2.y) + w3 * lo_f(h3.y);
    a[3] += w0 * hi_f(h0.y) + w1 * hi_f(h1.y) + w2 * hi_f(h2.y) + w3 * hi_f(h3.y);
    a[4] += w0 * lo_f(h0.z) + w1 * lo_f(h1.z) + w2 * lo_f(h2.z) + w3 * lo_f(h3.z);
    a[5] += w0 * hi_f(h0.z) + w1 * hi_f(h1.z) + w2 * hi_f(h2.z) + w3 * hi_f(h3.z);
    a[6] += w0 * lo_f(h0.w) + w1 * lo_f(h1.w) + w2 * lo_f(h2.w) + w3 * lo_f(h3.w);
    a[7] += w0 * hi_f(h0.w) + w1 * hi_f(h1.w) + w2 * hi_f(h2.w) + w3 * hi_f(h3.w);
    p = pn; k0 = n0; k1 = n1; k2 = n2; k3 = n3; have = haven;
  }
  for (; p < end; ++p) {
    u32 k = pack[p];
    uint4 hv = *reinterpret_cast<const uint4*>(&H[(size_t)(k & 0xFFFFu) * F + c0]);
    float wt = hi_f(k);
    a[0] += wt * lo_f(hv.x); a[1] += wt * hi_f(hv.x);
    a[2] += wt * lo_f(hv.y); a[3] += wt * hi_f(hv.y);
    a[4] += wt * lo_f(hv.z); a[5] += wt * hi_f(hv.z);
    a[6] += wt * lo_f(hv.w); a[7] += wt * hi_f(hv.w);
  }
  if (BIAS) {
    #pragma unroll
    for (int k = 0; k < 8; ++k) a[k] += bias[c0 + k];
  }
  if (ACT == 1) {
    #pragma unroll
    for (int k = 0; k < 8; ++k) a[k] = fast_tanh(a[k]);
  }
  if (OUT_BF16) {
    uint4 o;
    o.x = cvt_pk_bf16(a[0], a[1]);
    o.y = cvt_pk_bf16(a[2], a[3]);
    o.z = cvt_pk_bf16(a[4], a[5]);
    o.w = cvt_pk_bf16(a[6], a[7]);
    *reinterpret_cast<uint4*>(&((u16*)out)[(size_t)node * F + c0]) = o;
  } else {
    float* op = &((float*)out)[(size_t)node * F + c0];
    #pragma unroll
    for (int k = 0; k < 8; ++k) op[k] = a[k];
  }
}

// ---------------------------------------------------------------------------

extern "C" void kernel_launch(void* const* d_in, const int* in_sizes, int n_in,
                              void* d_out, int out_size, void* d_ws, size_t ws_size,
                              hipStream_t stream) {
  const int N = 20000, E = 320000;
  const int F_IN = 512, H1 = 1024, H2 = 512, F_OUT = 128;
  const int D1P = 256, D2P = 128;

  const float* x    = (const float*)d_in[0];
  const int*   src  = (const int*)d_in[1];
  const int*   dst  = (const int*)d_in[2];
  const float* ew   = (const float*)d_in[3];
  const float* W1   = (const float*)d_in[4];
  const float* b1   = (const float*)d_in[5];
  const float* W2   = (const float*)d_in[6];
  const float* b2   = (const float*)d_in[7];
  const float* W3   = (const float*)d_in[8];
  const float* b3   = (const float*)d_in[9];
  const float* Wd1  = (const float*)d_in[10];
  const float* bd1  = (const float*)d_in[11];
  const float* Wd2  = (const float*)d_in[12];
  const float* bd2  = (const float*)d_in[13];
  const float* Wd3  = (const float*)d_in[14];
  const float* bd3  = (const float*)d_in[15];
  float* out = (float*)d_out;

  size_t off = 0;
  auto alloc = [&](size_t bytes) {
    void* p = (char*)d_ws + off;
    off += (bytes + 255) & ~(size_t)255;
    return p;
  };
  u16* xb   = (u16*)alloc((size_t)MPAD * F_IN * 2);    // x bf16; later t2
  u16* ax   = (u16*)alloc((size_t)MPAD * F_IN * 2);    // A@x;   later h2
  u16* h1   = (u16*)alloc((size_t)MPAD * H1 * 2);      // h1 (also t3,gb,d1 region)
  u16* w1t  = (u16*)alloc((size_t)H1 * F_IN * 2);
  u16* w2t  = (u16*)alloc((size_t)H2 * H1 * 2);
  u16* w3t  = (u16*)alloc((size_t)F_OUT * H2 * 2);
  u16* wd1t = (u16*)alloc((size_t)D1P * F_OUT * 2);
  u16* wd2t = (u16*)alloc((size_t)D2P * D1P * 2);
  float* bd1p = (float*)alloc((size_t)D1P * 4);
  float* bd2p = (float*)alloc((size_t)D2P * 4);
  int* row_ptr = (int*)alloc((size_t)(N + 1) * 4);
  int* cnt1    = (int*)alloc((size_t)N * 4);
  int* cnt2    = (int*)alloc((size_t)N * 4);
  int* bsum    = (int*)alloc((size_t)32 * 4);
  u32* csr_pack = (u32*)alloc((size_t)E * 4);

  u16* t2 = xb;
  u16* h2 = ax;
  u16* t3 = h1;
  u16* gb = t3 + (size_t)MPAD * F_OUT;
  u16* d1 = gb + (size_t)MPAD * F_OUT;

  auto cdiv = [](int a, int b) { return (a + b - 1) / b; };
  const int NB32 = cdiv(N, 32);   // 625

  // ---- prep ----
  zero_cnt<<<cdiv(N, 256), 256, 0, stream>>>(cnt1, N);
  prep_all<<<12483, 256, 0, stream>>>(x, xb, W1, w1t, W2, w2t, W3, w3t,
                                      Wd1, wd1t, Wd2, wd2t, bd1, bd1p,
                                      bd2, bd2p, dst, cnt1, cnt2);
  scan_part<<<20, 1024, 0, stream>>>(cnt1, row_ptr, bsum, N);
  scan_fix<<<20, 1024, 0, stream>>>(row_ptr, bsum, N, 20);
  scatter_csr<<<cdiv(E, 256), 256, 0, stream>>>(dst, src, ew, row_ptr, cnt2,
                                                csr_pack, E);

  // ---- layer 1 (reordered): ax = A@x ; h1 = tanh(ax@W1 + b1) ----
  spmm_pl<512, 8, 0, false, true><<<NB32 * 8, 256, 0, stream>>>(
      row_ptr, csr_pack, xb, nullptr, ax, N);
  gemm_mfma_db<1, true, 1><<<dim3(H1 / 128, MPAD / 128), 256, 0, stream>>>(
      ax, w1t, b1, h1, MPAD, F_IN, H1, nullptr, nullptr, nullptr, 0);

  // ---- layer 2: t2 = h1@W2 ; h2 = tanh(A@t2 + b2) ----
  gemm_mfma_db<0, false, 1><<<dim3(H2 / 128, MPAD / 128), 256, 0, stream>>>(
      h1, w2t, nullptr, t2, MPAD, H1, H2, nullptr, nullptr, nullptr, 0);
  spmm_pl<512, 8, 1, true, true><<<NB32 * 8, 256, 0, stream>>>(
      row_ptr, csr_pack, t2, b2, h2, N);

  // ---- layer 3: t3 = h2@W3 ; gb = A@t3 + b3 (bf16) ----
  gemm_mfma_db<0, false, 1><<<dim3(F_OUT / 128, MPAD / 128), 256, 0, stream>>>(
      h2, w3t, nullptr, t3, MPAD, H2, F_OUT, nullptr, nullptr, nullptr, 0);
  spmm_pl<128, 2, 0, true, true><<<NB32 * 2, 256, 0, stream>>>(
      row_ptr, csr_pack, t3, b3, gb, N);

  // ---- dense head: d1 = relu(gb@Wd1+bd1); out = relu(d1@Wd2+bd2)@Wd3+bd3 ----
  gemm_mfma_db<2, true, 1><<<dim3(D1P / 128, MPAD / 128), 256, 0, stream>>>(
      gb, wd1t, bd1p, d1, MPAD, F_OUT, D1P, nullptr, nullptr, nullptr, 0);
  gemm_mfma_db<2, true, 2><<<dim3(D2P / 128, MPAD / 128), 256, 0, stream>>>(
      d1, wd2t, bd2p, nullptr, MPAD, D1P, D2P, Wd3, bd3, out, N);
}